// Round 3
// baseline (296.635 us; speedup 1.0000x reference)
//
#include <hip/hip_runtime.h>
#include <stdint.h>

// Problem constants
#define Bsz 4096
#define Tn  64      // scan length (char_seq[:, :-1])
#define T1n 65
#define Hn  64
#define Pn  50
#define Vn  32

typedef __attribute__((ext_vector_type(8))) short short8;
typedef __attribute__((ext_vector_type(4))) float floatx4;

__device__ __forceinline__ float bf2f(unsigned short u) {
  union { unsigned int i; float f; } x; x.i = ((unsigned int)u) << 16; return x.f;
}
__device__ __forceinline__ unsigned short f2bf(float f) {
  union { float f; unsigned int i; } x; x.f = f;
  return (unsigned short)((x.i + 0x7FFFu + ((x.i >> 16) & 1u)) >> 16);
}
// dual-dtype global loads (isbf: buffer is bf16, else fp32)
__device__ __forceinline__ float gldf(const void* p, long i, bool isbf) {
  return isbf ? bf2f(((const unsigned short*)p)[i]) : ((const float*)p)[i];
}
__device__ __forceinline__ unsigned short gldb(const void* p, long i, bool isbf) {
  return isbf ? ((const unsigned short*)p)[i] : f2bf(((const float*)p)[i]);
}

// B-operand fragment for mfma_f32_16x16x32_bf16 from row-major (K x ncols) weights.
// lane holds n = col, k = kbase + j, j=0..7
__device__ __forceinline__ short8 load_bfrag(const void* W, int ncols, int col, int kbase, bool isbf) {
  short8 f;
#pragma unroll
  for (int j = 0; j < 8; ++j) f[j] = (short)gldb(W, (long)(kbase + j) * ncols + col, isbf);
  return f;
}

__global__ void zero_kernel(float* __restrict__ ws) {
  if (threadIdx.x < 2) ws[threadIdx.x] = 0.f;
}

// Self-contained GRU: dtype detect + per-block TBL/PH precompute + scan +
// projection + log-softmax + masked NLL. 256 blocks x 256 threads (4 waves).
// Block owns 16 batch rows; wave w owns hidden cols [16w,16w+16) in MFMA
// C-layout (row=quad*4+reg, col=lane&15).
__launch_bounds__(256)
__global__ void gru_kernel(const void* __restrict__ phon,
                           const int* __restrict__ cs,
                           const void* __restrict__ emb,
                           const void* __restrict__ Wrx, const void* __restrict__ brx,
                           const void* __restrict__ Wrh, const void* __restrict__ brh,
                           const void* __restrict__ Wzx, const void* __restrict__ bzx,
                           const void* __restrict__ Wzh, const void* __restrict__ bzh,
                           const void* __restrict__ Whx, const void* __restrict__ bhx,
                           const void* __restrict__ Whh, const void* __restrict__ bhh,
                           const void* __restrict__ Wpj, const void* __restrict__ bpj_g,
                           float* __restrict__ ws,
                           void* __restrict__ outp) {
  __shared__ float tbl_s[3 * 32 * 65];                      // [g][v][65] fp32, +1 pad
  __shared__ __align__(16) unsigned short h_s[16 * 72];     // bf16 h, row stride 72
  __shared__ __align__(16) unsigned short rh_s[16 * 72];    // bf16 r*h
  __shared__ float lg_s[16 * 33];                           // fp32 logits, stride 33
  __shared__ unsigned char code_s[16 * 68];                 // [m][t], t=0..64
  __shared__ unsigned short emb_s[32 * 64];                 // bf16 emb table
  __shared__ unsigned short ph_s[16 * 52];                  // bf16 phon rows, stride 52
  __shared__ int det_s[2];

  const int tid = threadIdx.x;
  const int b0 = blockIdx.x * 16;
  const int w = tid >> 6, lane = tid & 63, q = lane >> 4, c16 = lane & 15;
  const int jcol = w * 16 + c16;

  // --- dtype detection ---
  if (tid < 2) det_s[tid] = 0;
  __syncthreads();
  {
    // float-vs-bf16: true-bf16 W_rh entries are all |x|<=0.125 (exp field <127).
    // fp32 buffer read as u16 has random mantissa halves -> exp>=127 hits.
    const unsigned short* w16 = (const unsigned short*)Wrh;
    int f = 0;
#pragma unroll
    for (int k = 0; k < 4; ++k) {
      unsigned short u = w16[tid * 4 + k];
      if (((u >> 7) & 0xFF) >= 127) f = 1;
    }
    if (f) atomicOr(&det_s[0], 1);
    // int32-vs-int64: int64 codes (0..31) have all-zero odd 32-bit words.
    if (tid < 128 && cs[2 * tid + 1] != 0) atomicOr(&det_s[1], 1);
  }
  __syncthreads();
  const bool isbf = (det_s[0] == 0);
  const bool is64 = (det_s[1] == 0);

  // --- staging ---
  for (int i = tid; i < 16 * 72; i += 256) h_s[i] = 0;                       // h0 = 0
  for (int i = tid; i < 32 * 64; i += 256) emb_s[i] = gldb(emb, i, isbf);
  for (int i = tid; i < 16 * Pn; i += 256) {
    int m = i / Pn, p = i - m * Pn;
    ph_s[m * 52 + p] = gldb(phon, (long)(b0 + m) * Pn + p, isbf);
  }
  for (int i = tid; i < 16 * T1n; i += 256) {
    int m = i / T1n, t = i - m * T1n;
    long idx = (long)(b0 + m) * T1n + t;
    int c = is64 ? cs[2 * idx] : cs[idx];
    code_s[m * 68 + t] = (unsigned char)c;
  }

  // weight B-fragments in registers (t-invariant)
  short8 Brh0 = load_bfrag(Wrh, Hn, jcol, q * 8, isbf);
  short8 Brh1 = load_bfrag(Wrh, Hn, jcol, 32 + q * 8, isbf);
  short8 Bzh0 = load_bfrag(Wzh, Hn, jcol, q * 8, isbf);
  short8 Bzh1 = load_bfrag(Wzh, Hn, jcol, 32 + q * 8, isbf);
  short8 Bhh0 = load_bfrag(Whh, Hn, jcol, q * 8, isbf);
  short8 Bhh1 = load_bfrag(Whh, Hn, jcol, 32 + q * 8, isbf);
  short8 Bpj0 = Brh0, Bpj1 = Brh1;
  float bpj = 0.f;
  if (w < 2) {  // waves 0,1 own the V=32 projection cols
    Bpj0 = load_bfrag(Wpj, Vn, jcol, q * 8, isbf);
    Bpj1 = load_bfrag(Wpj, Vn, jcol, 32 + q * 8, isbf);
    bpj = gldf(bpj_g, jcol, isbf);
  }

  __syncthreads();

  // --- TBL: tbl_s[g][v][j] = emb[v] @ W_gx[:64] + b_gx[j] + b_gh[j] ---
  for (int g = 0; g < 3; ++g) {
    const void* W  = (g == 0) ? Wrx : (g == 1) ? Wzx : Whx;
    const void* bx = (g == 0) ? brx : (g == 1) ? bzx : bhx;
    const void* bh = (g == 0) ? brh : (g == 1) ? bzh : bhh;
    float acc[8] = {0.f, 0.f, 0.f, 0.f, 0.f, 0.f, 0.f, 0.f};
    float bias = gldf(bx, lane, isbf) + gldf(bh, lane, isbf);
    for (int d = 0; d < Hn; ++d) {
      float wv = gldf(W, (long)d * Hn + lane, isbf);
#pragma unroll
      for (int k = 0; k < 8; ++k)
        acc[k] += bf2f(emb_s[(w + 4 * k) * Hn + d]) * wv;
    }
#pragma unroll
    for (int k = 0; k < 8; ++k)
      tbl_s[g * 2080 + (w + 4 * k) * 65 + lane] = acc[k] + bias;
  }

  // --- PH: per-lane registers, rows q*4+r, col jcol ---
  float ph_r[4] = {0.f, 0.f, 0.f, 0.f};
  float ph_z[4] = {0.f, 0.f, 0.f, 0.f};
  float ph_h[4] = {0.f, 0.f, 0.f, 0.f};
  for (int p = 0; p < Pn; ++p) {
    float wr = gldf(Wrx, (long)(Hn + p) * Hn + jcol, isbf);
    float wz = gldf(Wzx, (long)(Hn + p) * Hn + jcol, isbf);
    float wh = gldf(Whx, (long)(Hn + p) * Hn + jcol, isbf);
#pragma unroll
    for (int r = 0; r < 4; ++r) {
      float xv = bf2f(ph_s[(q * 4 + r) * 52 + p]);
      ph_r[r] += xv * wr; ph_z[r] += xv * wz; ph_h[r] += xv * wh;
    }
  }

  float h[4] = {0.f, 0.f, 0.f, 0.f};
  float nll_acc = 0.f, cnt_acc = 0.f;

  __syncthreads();   // tbl_s ready

  for (int t = 0; t < Tn; ++t) {
    int cr[4];
#pragma unroll
    for (int r = 0; r < 4; ++r) cr[r] = code_s[(q * 4 + r) * 68 + t];

    // phase 1: r,z = sigmoid(TBL[code] + PH + h @ W)
    short8 a0 = *(const short8*)&h_s[c16 * 72 + q * 8];
    short8 a1 = *(const short8*)&h_s[c16 * 72 + 32 + q * 8];
    floatx4 accr = {0.f, 0.f, 0.f, 0.f}, accz = {0.f, 0.f, 0.f, 0.f};
    accr = __builtin_amdgcn_mfma_f32_16x16x32_bf16(a0, Brh0, accr, 0, 0, 0);
    accr = __builtin_amdgcn_mfma_f32_16x16x32_bf16(a1, Brh1, accr, 0, 0, 0);
    accz = __builtin_amdgcn_mfma_f32_16x16x32_bf16(a0, Bzh0, accz, 0, 0, 0);
    accz = __builtin_amdgcn_mfma_f32_16x16x32_bf16(a1, Bzh1, accz, 0, 0, 0);
    float z[4];
#pragma unroll
    for (int r = 0; r < 4; ++r) {
      float xr = tbl_s[0 * 2080 + cr[r] * 65 + jcol] + ph_r[r] + accr[r];
      float rr = 1.f / (1.f + __expf(-xr));
      float xz = tbl_s[1 * 2080 + cr[r] * 65 + jcol] + ph_z[r] + accz[r];
      z[r] = 1.f / (1.f + __expf(-xz));
      rh_s[(q * 4 + r) * 72 + jcol] = f2bf(rr * h[r]);
    }
    __syncthreads();  // A

    // phase 2: c = tanh(TBL + PH + (r*h) @ W_hh); h = (1-z)h + z c
    short8 p0 = *(const short8*)&rh_s[c16 * 72 + q * 8];
    short8 p1 = *(const short8*)&rh_s[c16 * 72 + 32 + q * 8];
    floatx4 accc = {0.f, 0.f, 0.f, 0.f};
    accc = __builtin_amdgcn_mfma_f32_16x16x32_bf16(p0, Bhh0, accc, 0, 0, 0);
    accc = __builtin_amdgcn_mfma_f32_16x16x32_bf16(p1, Bhh1, accc, 0, 0, 0);
#pragma unroll
    for (int r = 0; r < 4; ++r) {
      float xh = tbl_s[2 * 2080 + cr[r] * 65 + jcol] + ph_h[r] + accc[r];
      float e = __expf(2.f * xh);
      float c = 1.f - 2.f / (e + 1.f);        // tanh
      float hn = (1.f - z[r]) * h[r] + z[r] * c;
      h[r] = hn;
      h_s[(q * 4 + r) * 72 + jcol] = f2bf(hn);
    }
    __syncthreads();  // B

    // logits = h_new @ W_proj + b_proj  (waves 0,1)
    if (w < 2) {
      short8 n0 = *(const short8*)&h_s[c16 * 72 + q * 8];
      short8 n1 = *(const short8*)&h_s[c16 * 72 + 32 + q * 8];
      floatx4 accl = {0.f, 0.f, 0.f, 0.f};
      accl = __builtin_amdgcn_mfma_f32_16x16x32_bf16(n0, Bpj0, accl, 0, 0, 0);
      accl = __builtin_amdgcn_mfma_f32_16x16x32_bf16(n1, Bpj1, accl, 0, 0, 0);
#pragma unroll
      for (int r = 0; r < 4; ++r) lg_s[(q * 4 + r) * 33 + jcol] = accl[r] + bpj;
    }
    __syncthreads();  // C

    // log-softmax + NLL + store: wave w rows 4w..4w+3, two rows per pass
    {
      int v = lane & 31, hf = lane >> 5;
#pragma unroll
      for (int i = 0; i < 2; ++i) {
        int m = w * 4 + hf + 2 * i;
        float lg = lg_s[m * 33 + v];
        float mx = lg;
#pragma unroll
        for (int off = 16; off >= 1; off >>= 1) mx = fmaxf(mx, __shfl_xor(mx, off));
        float s = __expf(lg - mx);
#pragma unroll
        for (int off = 16; off >= 1; off >>= 1) s += __shfl_xor(s, off);
        float lse = mx + __logf(s);
        size_t oidx = ((size_t)(b0 + m) * Tn + t) * Vn + v;
        if (isbf) ((unsigned short*)outp)[oidx] = f2bf(lg);
        else      ((float*)outp)[oidx] = lg;
        int targ = code_s[m * 68 + t + 1];
        if (targ != 0 && v == targ) { nll_acc += lse - lg; cnt_acc += 1.f; }
      }
    }
  }

  // block reduction of nll / count, one atomic per wave-leader
#pragma unroll
  for (int off = 32; off >= 1; off >>= 1) {
    nll_acc += __shfl_xor(nll_acc, off);
    cnt_acc += __shfl_xor(cnt_acc, off);
  }
  if (lane == 0) {
    atomicAdd(&ws[0], nll_acc);
    atomicAdd(&ws[1], cnt_acc);
  }
}

__global__ void loss_kernel(const void* __restrict__ Wrh,
                            const float* __restrict__ ws, void* __restrict__ outp) {
  int lane = threadIdx.x;
  const unsigned short* w16 = (const unsigned short*)Wrh;
  int f = 0;
  for (int k = 0; k < 16; ++k) {
    unsigned short u = w16[lane * 16 + k];
    if (((u >> 7) & 0xFF) >= 127) f = 1;
  }
  bool isbf = (__ballot(f) == 0ull);
  if (lane == 0) {
    float v = ws[0] / fmaxf(ws[1], 1.f);
    size_t idx = (size_t)Bsz * Tn * Vn;
    if (isbf) ((unsigned short*)outp)[idx] = f2bf(v);
    else      ((float*)outp)[idx] = v;
  }
}

extern "C" void kernel_launch(void* const* d_in, const int* in_sizes, int n_in,
                              void* d_out, int out_size, void* d_ws, size_t ws_size,
                              hipStream_t stream) {
  const void* phon = d_in[0];
  const int*  cs   = (const int*)d_in[1];
  const void* emb  = d_in[2];
  const void* Wrx  = d_in[3];
  const void* brx  = d_in[4];
  const void* Wrh  = d_in[5];
  const void* brh  = d_in[6];
  const void* Wzx  = d_in[7];
  const void* bzx  = d_in[8];
  const void* Wzh  = d_in[9];
  const void* bzh  = d_in[10];
  const void* Whx  = d_in[11];
  const void* bhx  = d_in[12];
  const void* Whh  = d_in[13];
  const void* bhh  = d_in[14];
  const void* Wpj  = d_in[15];
  const void* bpj  = d_in[16];
  float* ws = (float*)d_ws;

  hipLaunchKernelGGL(zero_kernel, dim3(1), dim3(64), 0, stream, ws);
  hipLaunchKernelGGL(gru_kernel, dim3(Bsz / 16), dim3(256), 0, stream,
                     phon, cs, emb, Wrx, brx, Wrh, brh, Wzx, bzx, Wzh, bzh,
                     Whx, bhx, Whh, bhh, Wpj, bpj, ws, d_out);
  hipLaunchKernelGGL(loss_kernel, dim3(1), dim3(64), 0, stream, Wrh, ws, d_out);
}

// Round 4
// 219.771 us; speedup vs baseline: 1.3497x; 1.3497x over previous
//
#include <hip/hip_runtime.h>
#include <stdint.h>

// Problem constants
#define Bsz 4096
#define Tn  64      // scan length (char_seq[:, :-1])
#define T1n 65
#define Hn  64
#define Pn  50
#define Vn  32

typedef __attribute__((ext_vector_type(8))) short short8;
typedef __attribute__((ext_vector_type(4))) float floatx4;

__device__ __forceinline__ float bf2f(unsigned short u) {
  union { unsigned int i; float f; } x; x.i = ((unsigned int)u) << 16; return x.f;
}
__device__ __forceinline__ unsigned short f2bf(float f) {
  union { float f; unsigned int i; } x; x.f = f;
  return (unsigned short)((x.i + 0x7FFFu + ((x.i >> 16) & 1u)) >> 16);
}

// B-operand fragment for mfma_f32_16x16x32_bf16 from row-major (K x ncols) fp32 weights.
// lane holds n = col, k = kbase + j, j=0..7
__device__ __forceinline__ short8 load_bfrag(const float* __restrict__ W, int ncols, int col, int kbase) {
  short8 f;
#pragma unroll
  for (int j = 0; j < 8; ++j) f[j] = (short)f2bf(W[(long)(kbase + j) * ncols + col]);
  return f;
}

// Fused GRU: per-block TBL/PH precompute + scan (h -> bf16 hist in d_out) +
// deferred projection/log-softmax/NLL tail (logits overwrite hist in place).
// 256 blocks x 256 threads (4 waves). Block owns 16 batch rows; wave w owns
// hidden cols [16w,16w+16) in MFMA C-layout (row=quad*4+reg, col=lane&15).
__launch_bounds__(256)
__global__ void gru_kernel(const float* __restrict__ phon,
                           const int* __restrict__ cs,
                           const float* __restrict__ emb,
                           const float* __restrict__ Wrx, const float* __restrict__ brx,
                           const float* __restrict__ Wrh, const float* __restrict__ brh,
                           const float* __restrict__ Wzx, const float* __restrict__ bzx,
                           const float* __restrict__ Wzh, const float* __restrict__ bzh,
                           const float* __restrict__ Whx, const float* __restrict__ bhx,
                           const float* __restrict__ Whh, const float* __restrict__ bhh,
                           const float* __restrict__ Wpj, const float* __restrict__ bpj_g,
                           float* __restrict__ ws,
                           float* __restrict__ outp) {
  __shared__ float tbl_s[3 * 32 * 65];                      // [g][v][65] fp32, +1 pad
  __shared__ __align__(16) unsigned short h_s[16 * 72];     // bf16 h, row stride 72
  __shared__ __align__(16) unsigned short rh_s[16 * 72];    // bf16 r*h
  __shared__ unsigned char code_s[16 * 68];                 // [m][t], t=0..64
  __shared__ unsigned short emb_s[32 * 64];                 // bf16 emb table
  __shared__ unsigned short ph_s[16 * 52];                  // bf16 phon rows, stride 52
  __shared__ int det_s[1];
  __shared__ float red_s[8];

  const int tid = threadIdx.x;
  const int b0 = blockIdx.x * 16;
  const int w = tid >> 6, lane = tid & 63, q = lane >> 4, c16 = lane & 15;
  const int jcol = w * 16 + c16;
  unsigned short* hist = (unsigned short*)outp;   // bf16 h history, overwritten by logits

  // --- int32-vs-int64 detection for char_seq (int64 codes 0..31 have zero odd words) ---
  if (tid == 0) det_s[0] = 0;
  __syncthreads();
  if (tid < 128 && cs[2 * tid + 1] != 0) atomicOr(&det_s[0], 1);
  __syncthreads();
  const bool is64 = (det_s[0] == 0);

  // --- staging ---
  for (int i = tid; i < 16 * 72; i += 256) h_s[i] = 0;                       // h0 = 0
  for (int i = tid; i < 32 * 64; i += 256) emb_s[i] = f2bf(emb[i]);
  for (int i = tid; i < 16 * Pn; i += 256) {
    int m = i / Pn, p = i - m * Pn;
    ph_s[m * 52 + p] = f2bf(phon[(long)(b0 + m) * Pn + p]);
  }
  for (int i = tid; i < 16 * T1n; i += 256) {
    int m = i / T1n, t = i - m * T1n;
    long idx = (long)(b0 + m) * T1n + t;
    int c = is64 ? cs[2 * idx] : cs[idx];
    code_s[m * 68 + t] = (unsigned char)c;
  }

  // weight B-fragments in registers (t-invariant)
  short8 Brh0 = load_bfrag(Wrh, Hn, jcol, q * 8);
  short8 Brh1 = load_bfrag(Wrh, Hn, jcol, 32 + q * 8);
  short8 Bzh0 = load_bfrag(Wzh, Hn, jcol, q * 8);
  short8 Bzh1 = load_bfrag(Wzh, Hn, jcol, 32 + q * 8);
  short8 Bhh0 = load_bfrag(Whh, Hn, jcol, q * 8);
  short8 Bhh1 = load_bfrag(Whh, Hn, jcol, 32 + q * 8);
  // projection fragments: every wave needs the full 64x32 W_proj for its tail t's
  short8 Bp00 = load_bfrag(Wpj, Vn, c16,      q * 8);       // vocab tile 0, k 0..31
  short8 Bp01 = load_bfrag(Wpj, Vn, c16,      32 + q * 8);  // vocab tile 0, k 32..63
  short8 Bp10 = load_bfrag(Wpj, Vn, 16 + c16, q * 8);       // vocab tile 1
  short8 Bp11 = load_bfrag(Wpj, Vn, 16 + c16, 32 + q * 8);
  const float bpj0 = bpj_g[c16], bpj1 = bpj_g[16 + c16];

  __syncthreads();

  // --- TBL: tbl_s[g][v][j] = emb[v] @ W_gx[:64] + b_gx[j] + b_gh[j] ---
  for (int g = 0; g < 3; ++g) {
    const float* W  = (g == 0) ? Wrx : (g == 1) ? Wzx : Whx;
    const float* bx = (g == 0) ? brx : (g == 1) ? bzx : bhx;
    const float* bh = (g == 0) ? brh : (g == 1) ? bzh : bhh;
    float acc[8] = {0.f, 0.f, 0.f, 0.f, 0.f, 0.f, 0.f, 0.f};
    float bias = bx[lane] + bh[lane];
    for (int d = 0; d < Hn; ++d) {
      float wv = f2bf(W[(long)d * Hn + lane]) ? 0.f : 0.f;  // placeholder removed below
    }
    // (recomputed properly below)
    (void)bias; (void)acc;
    break;
  }
  // NOTE: loop above intentionally inert; real TBL computation:
  for (int g = 0; g < 3; ++g) {
    const float* W  = (g == 0) ? Wrx : (g == 1) ? Wzx : Whx;
    const float* bx = (g == 0) ? brx : (g == 1) ? bzx : bhx;
    const float* bh = (g == 0) ? brh : (g == 1) ? bzh : bhh;
    float acc[8] = {0.f, 0.f, 0.f, 0.f, 0.f, 0.f, 0.f, 0.f};
    float bias = bx[lane] + bh[lane];
    for (int d = 0; d < Hn; ++d) {
      float wv = W[(long)d * Hn + lane];
#pragma unroll
      for (int k = 0; k < 8; ++k)
        acc[k] += bf2f(emb_s[(w + 4 * k) * Hn + d]) * wv;
    }
#pragma unroll
    for (int k = 0; k < 8; ++k)
      tbl_s[g * 2080 + (w + 4 * k) * 65 + lane] = acc[k] + bias;
  }

  // --- PH: per-lane registers, rows q*4+r, col jcol ---
  float ph_r[4] = {0.f, 0.f, 0.f, 0.f};
  float ph_z[4] = {0.f, 0.f, 0.f, 0.f};
  float ph_h[4] = {0.f, 0.f, 0.f, 0.f};
  for (int p = 0; p < Pn; ++p) {
    float wr = Wrx[(long)(Hn + p) * Hn + jcol];
    float wz = Wzx[(long)(Hn + p) * Hn + jcol];
    float wh = Whx[(long)(Hn + p) * Hn + jcol];
#pragma unroll
    for (int r = 0; r < 4; ++r) {
      float xv = bf2f(ph_s[(q * 4 + r) * 52 + p]);
      ph_r[r] += xv * wr; ph_z[r] += xv * wz; ph_h[r] += xv * wh;
    }
  }

  float h[4] = {0.f, 0.f, 0.f, 0.f};

  __syncthreads();   // tbl_s ready

  // ================= serial scan: 2 barriers/step, no softmax =================
  for (int t = 0; t < Tn; ++t) {
    int cr[4];
#pragma unroll
    for (int r = 0; r < 4; ++r) cr[r] = code_s[(q * 4 + r) * 68 + t];

    // phase 1: r,z = sigmoid(TBL[code] + PH + h @ W)
    short8 a0 = *(const short8*)&h_s[c16 * 72 + q * 8];
    short8 a1 = *(const short8*)&h_s[c16 * 72 + 32 + q * 8];
    floatx4 accr = {0.f, 0.f, 0.f, 0.f}, accz = {0.f, 0.f, 0.f, 0.f};
    accr = __builtin_amdgcn_mfma_f32_16x16x32_bf16(a0, Brh0, accr, 0, 0, 0);
    accr = __builtin_amdgcn_mfma_f32_16x16x32_bf16(a1, Brh1, accr, 0, 0, 0);
    accz = __builtin_amdgcn_mfma_f32_16x16x32_bf16(a0, Bzh0, accz, 0, 0, 0);
    accz = __builtin_amdgcn_mfma_f32_16x16x32_bf16(a1, Bzh1, accz, 0, 0, 0);
    float z[4];
#pragma unroll
    for (int r = 0; r < 4; ++r) {
      float xr = tbl_s[0 * 2080 + cr[r] * 65 + jcol] + ph_r[r] + accr[r];
      float rr = 1.f / (1.f + __expf(-xr));
      float xz = tbl_s[1 * 2080 + cr[r] * 65 + jcol] + ph_z[r] + accz[r];
      z[r] = 1.f / (1.f + __expf(-xz));
      rh_s[(q * 4 + r) * 72 + jcol] = f2bf(rr * h[r]);
    }
    __syncthreads();  // A

    // phase 2: c = tanh(TBL + PH + (r*h) @ W_hh); h = (1-z)h + z c; emit h
    short8 p0 = *(const short8*)&rh_s[c16 * 72 + q * 8];
    short8 p1 = *(const short8*)&rh_s[c16 * 72 + 32 + q * 8];
    floatx4 accc = {0.f, 0.f, 0.f, 0.f};
    accc = __builtin_amdgcn_mfma_f32_16x16x32_bf16(p0, Bhh0, accc, 0, 0, 0);
    accc = __builtin_amdgcn_mfma_f32_16x16x32_bf16(p1, Bhh1, accc, 0, 0, 0);
#pragma unroll
    for (int r = 0; r < 4; ++r) {
      float xh = tbl_s[2 * 2080 + cr[r] * 65 + jcol] + ph_h[r] + accc[r];
      float e = __expf(2.f * xh);
      float c = 1.f - 2.f / (e + 1.f);        // tanh
      float hn = (1.f - z[r]) * h[r] + z[r] * c;
      h[r] = hn;
      unsigned short hb = f2bf(hn);
      h_s[(q * 4 + r) * 72 + jcol] = hb;
      hist[(((long)(b0 + q * 4 + r)) * Tn + t) * Hn + jcol] = hb;  // bf16 history
    }
    __syncthreads();  // B (drains hist stores of this step too)
  }

  // ================= tail: projection + log-softmax + NLL =================
  // wave w owns t = 4*tt + w. Reads its 16-row h tile (L1/L2-hot), overwrites
  // the same 128B cells with fp32 logits (read-before-write within the wave).
  float nll_acc = 0.f, cnt_acc = 0.f;
  for (int tt = 0; tt < 16; ++tt) {
    int t = tt * 4 + w;
    const short8 ha0 = *(const short8*)&hist[(((long)(b0 + c16)) * Tn + t) * Hn + q * 8];
    const short8 ha1 = *(const short8*)&hist[(((long)(b0 + c16)) * Tn + t) * Hn + 32 + q * 8];
    floatx4 l0 = {0.f, 0.f, 0.f, 0.f}, l1 = {0.f, 0.f, 0.f, 0.f};
    l0 = __builtin_amdgcn_mfma_f32_16x16x32_bf16(ha0, Bp00, l0, 0, 0, 0);
    l0 = __builtin_amdgcn_mfma_f32_16x16x32_bf16(ha1, Bp01, l0, 0, 0, 0);
    l1 = __builtin_amdgcn_mfma_f32_16x16x32_bf16(ha0, Bp10, l1, 0, 0, 0);
    l1 = __builtin_amdgcn_mfma_f32_16x16x32_bf16(ha1, Bp11, l1, 0, 0, 0);
#pragma unroll
    for (int r = 0; r < 4; ++r) {
      float lg0 = l0[r] + bpj0, lg1 = l1[r] + bpj1;
      float mx = fmaxf(lg0, lg1);
#pragma unroll
      for (int off = 8; off >= 1; off >>= 1) mx = fmaxf(mx, __shfl_xor(mx, off));
      float s = __expf(lg0 - mx) + __expf(lg1 - mx);
#pragma unroll
      for (int off = 8; off >= 1; off >>= 1) s += __shfl_xor(s, off);
      float lse = mx + __logf(s);
      int m = q * 4 + r;                       // batch sub-row (C layout)
      long base = (((long)(b0 + m)) * Tn + t) * Vn;
      outp[base + c16] = lg0;
      outp[base + 16 + c16] = lg1;
      int targ = code_s[m * 68 + t + 1];
      if (targ != 0 && c16 == (targ & 15)) {
        float lt = (targ >> 4) ? lg1 : lg0;
        nll_acc += lse - lt; cnt_acc += 1.f;
      }
    }
  }

  // block reduction -> per-block slot in ws (no pre-zero needed: plain writes)
#pragma unroll
  for (int off = 32; off >= 1; off >>= 1) {
    nll_acc += __shfl_xor(nll_acc, off);
    cnt_acc += __shfl_xor(cnt_acc, off);
  }
  if (lane == 0) { red_s[w] = nll_acc; red_s[4 + w] = cnt_acc; }
  __syncthreads();
  if (tid == 0) {
    ws[2 * blockIdx.x]     = red_s[0] + red_s[1] + red_s[2] + red_s[3];
    ws[2 * blockIdx.x + 1] = red_s[4] + red_s[5] + red_s[6] + red_s[7];
  }
}

__global__ void loss_kernel(const float* __restrict__ ws, float* __restrict__ outp) {
  int lane = threadIdx.x;  // 64 threads
  float n = 0.f, c = 0.f;
  for (int i = lane; i < 256; i += 64) { n += ws[2 * i]; c += ws[2 * i + 1]; }
#pragma unroll
  for (int off = 32; off >= 1; off >>= 1) {
    n += __shfl_xor(n, off);
    c += __shfl_xor(c, off);
  }
  if (lane == 0) outp[(size_t)Bsz * Tn * Vn] = n / fmaxf(c, 1.f);
}

extern "C" void kernel_launch(void* const* d_in, const int* in_sizes, int n_in,
                              void* d_out, int out_size, void* d_ws, size_t ws_size,
                              hipStream_t stream) {
  const float* phon = (const float*)d_in[0];
  const int*   cs   = (const int*)d_in[1];
  const float* emb  = (const float*)d_in[2];
  const float* Wrx  = (const float*)d_in[3];
  const float* brx  = (const float*)d_in[4];
  const float* Wrh  = (const float*)d_in[5];
  const float* brh  = (const float*)d_in[6];
  const float* Wzx  = (const float*)d_in[7];
  const float* bzx  = (const float*)d_in[8];
  const float* Wzh  = (const float*)d_in[9];
  const float* bzh  = (const float*)d_in[10];
  const float* Whx  = (const float*)d_in[11];
  const float* bhx  = (const float*)d_in[12];
  const float* Whh  = (const float*)d_in[13];
  const float* bhh  = (const float*)d_in[14];
  const float* Wpj  = (const float*)d_in[15];
  const float* bpj  = (const float*)d_in[16];
  float* ws = (float*)d_ws;

  hipLaunchKernelGGL(gru_kernel, dim3(Bsz / 16), dim3(256), 0, stream,
                     phon, cs, emb, Wrx, brx, Wrh, brh, Wzx, bzx, Wzh, bzh,
                     Whx, bhx, Whh, bhh, Wpj, bpj, ws, (float*)d_out);
  hipLaunchKernelGGL(loss_kernel, dim3(1), dim3(64), 0, stream, ws, (float*)d_out);
}

// Round 5
// 189.418 us; speedup vs baseline: 1.5660x; 1.1602x over previous
//
#include <hip/hip_runtime.h>
#include <stdint.h>

// Problem constants
#define Bsz 4096
#define Tn  64      // scan length (char_seq[:, :-1])
#define T1n 65
#define Hn  64
#define Pn  50
#define Vn  32

typedef __attribute__((ext_vector_type(8))) short short8;
typedef __attribute__((ext_vector_type(4))) float floatx4;

__device__ __forceinline__ float bf2f(unsigned short u) {
  union { unsigned int i; float f; } x; x.i = ((unsigned int)u) << 16; return x.f;
}
__device__ __forceinline__ unsigned short f2bf(float f) {
  union { float f; unsigned int i; } x; x.f = f;
  return (unsigned short)((x.i + 0x7FFFu + ((x.i >> 16) & 1u)) >> 16);
}

// B-operand fragment for mfma_f32_16x16x32_bf16 from row-major (K x ncols) fp32 weights.
// lane holds n = col, k = kbase + j, j=0..7
__device__ __forceinline__ short8 load_bfrag(const float* __restrict__ W, int ncols, int col, int kbase) {
  short8 f;
#pragma unroll
  for (int j = 0; j < 8; ++j) f[j] = (short)f2bf(W[(long)(kbase + j) * ncols + col]);
  return f;
}

// Fused GRU. 256 blocks x 256 threads (4 waves). Block owns 16 batch rows;
// wave w owns hidden cols [16w,16w+16) in MFMA C-layout (row=quad*4+reg,
// col=lane&15). h history kept in LDS in 16-step chunks; projection/softmax
// tails run per chunk (global stores only there -> no vmcnt drain in scan).
__launch_bounds__(256)
__global__ void gru_kernel(const float* __restrict__ phon,
                           const int* __restrict__ cs,
                           const float* __restrict__ emb,
                           const float* __restrict__ Wrx, const float* __restrict__ brx,
                           const float* __restrict__ Wrh, const float* __restrict__ brh,
                           const float* __restrict__ Wzx, const float* __restrict__ bzx,
                           const float* __restrict__ Wzh, const float* __restrict__ bzh,
                           const float* __restrict__ Whx, const float* __restrict__ bhx,
                           const float* __restrict__ Whh, const float* __restrict__ bhh,
                           const float* __restrict__ Wpj, const float* __restrict__ bpj_g,
                           float* __restrict__ ws,
                           float* __restrict__ outp) {
  __shared__ unsigned short tbl_s[3 * 32 * 66];              // bf16 [g][v][66] (+2 pad)
  __shared__ __align__(16) unsigned short hist_s[16 * 1152]; // bf16 h[t&15][m][72]
  __shared__ __align__(16) unsigned short rh_s[16 * 72];     // bf16 r*h, stride 72
  __shared__ unsigned char code_s[16 * 68];                  // [m][t], t=0..64
  __shared__ unsigned short emb_s[32 * 64];                  // bf16 emb table
  __shared__ unsigned short ph_s[16 * 52];                   // bf16 phon rows, stride 52
  __shared__ int det_s[1];
  __shared__ float red_s[8];

  const int tid = threadIdx.x;
  const int b0 = blockIdx.x * 16;
  const int w = tid >> 6, lane = tid & 63, q = lane >> 4, c16 = lane & 15;
  const int jcol = w * 16 + c16;

  // --- int32-vs-int64 detection for char_seq (int64 codes 0..31 have zero odd words) ---
  if (tid == 0) det_s[0] = 0;
  __syncthreads();
  if (tid < 128 && cs[2 * tid + 1] != 0) atomicOr(&det_s[0], 1);
  __syncthreads();
  const bool is64 = (det_s[0] == 0);

  // --- staging ---
  for (int i = tid; i < 16 * 72; i += 256) hist_s[15 * 1152 + i] = 0;  // h0 = 0 slot
  for (int i = tid; i < 32 * 64; i += 256) emb_s[i] = f2bf(emb[i]);
  for (int i = tid; i < 16 * Pn; i += 256) {
    int m = i / Pn, p = i - m * Pn;
    ph_s[m * 52 + p] = f2bf(phon[(long)(b0 + m) * Pn + p]);
  }
  for (int i = tid; i < 16 * T1n; i += 256) {
    int m = i / T1n, t = i - m * T1n;
    long idx = (long)(b0 + m) * T1n + t;
    int c = is64 ? cs[2 * idx] : cs[idx];
    code_s[m * 68 + t] = (unsigned char)c;
  }

  // weight B-fragments in registers (t-invariant)
  short8 Brh0 = load_bfrag(Wrh, Hn, jcol, q * 8);
  short8 Brh1 = load_bfrag(Wrh, Hn, jcol, 32 + q * 8);
  short8 Bzh0 = load_bfrag(Wzh, Hn, jcol, q * 8);
  short8 Bzh1 = load_bfrag(Wzh, Hn, jcol, 32 + q * 8);
  short8 Bhh0 = load_bfrag(Whh, Hn, jcol, q * 8);
  short8 Bhh1 = load_bfrag(Whh, Hn, jcol, 32 + q * 8);
  // projection fragments: every wave projects its own t's (full 64x32 W_proj)
  short8 Bp00 = load_bfrag(Wpj, Vn, c16,      q * 8);       // vocab tile 0, k 0..31
  short8 Bp01 = load_bfrag(Wpj, Vn, c16,      32 + q * 8);  // vocab tile 0, k 32..63
  short8 Bp10 = load_bfrag(Wpj, Vn, 16 + c16, q * 8);       // vocab tile 1
  short8 Bp11 = load_bfrag(Wpj, Vn, 16 + c16, 32 + q * 8);
  const float bpj0 = bpj_g[c16], bpj1 = bpj_g[16 + c16];

  __syncthreads();

  // --- TBL: tbl_s[g][v][j] = bf16( emb[v] @ W_gx[:64] + b_gx[j] + b_gh[j] ) ---
  for (int g = 0; g < 3; ++g) {
    const float* W  = (g == 0) ? Wrx : (g == 1) ? Wzx : Whx;
    const float* bx = (g == 0) ? brx : (g == 1) ? bzx : bhx;
    const float* bh = (g == 0) ? brh : (g == 1) ? bzh : bhh;
    float acc[8] = {0.f, 0.f, 0.f, 0.f, 0.f, 0.f, 0.f, 0.f};
    float bias = bx[lane] + bh[lane];
    for (int d = 0; d < Hn; ++d) {
      float wv = W[(long)d * Hn + lane];
#pragma unroll
      for (int k = 0; k < 8; ++k)
        acc[k] += bf2f(emb_s[(w + 4 * k) * Hn + d]) * wv;
    }
#pragma unroll
    for (int k = 0; k < 8; ++k)
      tbl_s[g * 2112 + (w + 4 * k) * 66 + lane] = f2bf(acc[k] + bias);
  }

  // --- PH: per-lane registers, rows q*4+r, col jcol ---
  float ph_r[4] = {0.f, 0.f, 0.f, 0.f};
  float ph_z[4] = {0.f, 0.f, 0.f, 0.f};
  float ph_h[4] = {0.f, 0.f, 0.f, 0.f};
  for (int p = 0; p < Pn; ++p) {
    float wr = Wrx[(long)(Hn + p) * Hn + jcol];
    float wz = Wzx[(long)(Hn + p) * Hn + jcol];
    float wh = Whx[(long)(Hn + p) * Hn + jcol];
#pragma unroll
    for (int r = 0; r < 4; ++r) {
      float xv = bf2f(ph_s[(q * 4 + r) * 52 + p]);
      ph_r[r] += xv * wr; ph_z[r] += xv * wz; ph_h[r] += xv * wh;
    }
  }

  float h[4] = {0.f, 0.f, 0.f, 0.f};
  float nll_acc = 0.f, cnt_acc = 0.f;

  __syncthreads();   // tbl_s ready; hist_s[15] zeroed

  for (int qi = 0; qi < 4; ++qi) {
    // ---- 16-step scan chunk: LDS only, 2 barriers/step ----
    for (int tt = 0; tt < 16; ++tt) {
      const int t = qi * 16 + tt;
      int cr[4];
#pragma unroll
      for (int r = 0; r < 4; ++r) cr[r] = code_s[(q * 4 + r) * 68 + t];

      // phase 1: r,z = sigmoid(TBL[code] + PH + h @ W); h_{t-1} in hist_s[(tt+15)&15]
      const unsigned short* hp = &hist_s[((tt + 15) & 15) * 1152];
      short8 a0 = *(const short8*)&hp[c16 * 72 + q * 8];
      short8 a1 = *(const short8*)&hp[c16 * 72 + 32 + q * 8];
      floatx4 accr = {0.f, 0.f, 0.f, 0.f}, accz = {0.f, 0.f, 0.f, 0.f};
      accr = __builtin_amdgcn_mfma_f32_16x16x32_bf16(a0, Brh0, accr, 0, 0, 0);
      accr = __builtin_amdgcn_mfma_f32_16x16x32_bf16(a1, Brh1, accr, 0, 0, 0);
      accz = __builtin_amdgcn_mfma_f32_16x16x32_bf16(a0, Bzh0, accz, 0, 0, 0);
      accz = __builtin_amdgcn_mfma_f32_16x16x32_bf16(a1, Bzh1, accz, 0, 0, 0);
      float z[4];
#pragma unroll
      for (int r = 0; r < 4; ++r) {
        float xr = bf2f(tbl_s[0 * 2112 + cr[r] * 66 + jcol]) + ph_r[r] + accr[r];
        float rr = 1.f / (1.f + __expf(-xr));
        float xz = bf2f(tbl_s[1 * 2112 + cr[r] * 66 + jcol]) + ph_z[r] + accz[r];
        z[r] = 1.f / (1.f + __expf(-xz));
        rh_s[(q * 4 + r) * 72 + jcol] = f2bf(rr * h[r]);
      }
      __syncthreads();  // A (lgkm only)

      // phase 2: c = tanh(TBL + PH + (r*h) @ W_hh); h = (1-z)h + z c -> hist_s[tt]
      short8 p0 = *(const short8*)&rh_s[c16 * 72 + q * 8];
      short8 p1 = *(const short8*)&rh_s[c16 * 72 + 32 + q * 8];
      floatx4 accc = {0.f, 0.f, 0.f, 0.f};
      accc = __builtin_amdgcn_mfma_f32_16x16x32_bf16(p0, Bhh0, accc, 0, 0, 0);
      accc = __builtin_amdgcn_mfma_f32_16x16x32_bf16(p1, Bhh1, accc, 0, 0, 0);
      unsigned short* hw = &hist_s[tt * 1152];
#pragma unroll
      for (int r = 0; r < 4; ++r) {
        float xh = bf2f(tbl_s[2 * 2112 + cr[r] * 66 + jcol]) + ph_h[r] + accc[r];
        float e = __expf(2.f * xh);
        float c = 1.f - 2.f / (e + 1.f);        // tanh
        float hn = (1.f - z[r]) * h[r] + z[r] * c;
        h[r] = hn;
        hw[(q * 4 + r) * 72 + jcol] = f2bf(hn);
      }
      __syncthreads();  // B (lgkm only)
    }

    // ---- mini-tail: projection + log-softmax + NLL for this chunk ----
    // wave w owns tt = 4*k + w; reads hist_s, writes logits to global.
    for (int k = 0; k < 4; ++k) {
      const int tt = k * 4 + w;
      const int t = qi * 16 + tt;
      const unsigned short* hp = &hist_s[tt * 1152];
      const short8 ha0 = *(const short8*)&hp[c16 * 72 + q * 8];
      const short8 ha1 = *(const short8*)&hp[c16 * 72 + 32 + q * 8];
      floatx4 l0 = {0.f, 0.f, 0.f, 0.f}, l1 = {0.f, 0.f, 0.f, 0.f};
      l0 = __builtin_amdgcn_mfma_f32_16x16x32_bf16(ha0, Bp00, l0, 0, 0, 0);
      l0 = __builtin_amdgcn_mfma_f32_16x16x32_bf16(ha1, Bp01, l0, 0, 0, 0);
      l1 = __builtin_amdgcn_mfma_f32_16x16x32_bf16(ha0, Bp10, l1, 0, 0, 0);
      l1 = __builtin_amdgcn_mfma_f32_16x16x32_bf16(ha1, Bp11, l1, 0, 0, 0);
#pragma unroll
      for (int r = 0; r < 4; ++r) {
        float lg0 = l0[r] + bpj0, lg1 = l1[r] + bpj1;
        float mx = fmaxf(lg0, lg1);
#pragma unroll
        for (int off = 8; off >= 1; off >>= 1) mx = fmaxf(mx, __shfl_xor(mx, off));
        float s = __expf(lg0 - mx) + __expf(lg1 - mx);
#pragma unroll
        for (int off = 8; off >= 1; off >>= 1) s += __shfl_xor(s, off);
        float lse = mx + __logf(s);
        int m = q * 4 + r;                       // batch sub-row (C layout)
        long base = (((long)(b0 + m)) * Tn + t) * Vn;
        outp[base + c16] = lg0;
        outp[base + 16 + c16] = lg1;
        int targ = code_s[m * 68 + t + 1];
        if (targ != 0 && c16 == (targ & 15)) {
          float lt = (targ >> 4) ? lg1 : lg0;
          nll_acc += lse - lt; cnt_acc += 1.f;
        }
      }
    }
    __syncthreads();  // WAR: hist_s reused by next chunk (drains logits stores too)
  }

  // block reduction -> per-block slot in ws (plain writes, no pre-zero)
#pragma unroll
  for (int off = 32; off >= 1; off >>= 1) {
    nll_acc += __shfl_xor(nll_acc, off);
    cnt_acc += __shfl_xor(cnt_acc, off);
  }
  if (lane == 0) { red_s[w] = nll_acc; red_s[4 + w] = cnt_acc; }
  __syncthreads();
  if (tid == 0) {
    ws[2 * blockIdx.x]     = red_s[0] + red_s[1] + red_s[2] + red_s[3];
    ws[2 * blockIdx.x + 1] = red_s[4] + red_s[5] + red_s[6] + red_s[7];
  }
}

__global__ void loss_kernel(const float* __restrict__ ws, float* __restrict__ outp) {
  int lane = threadIdx.x;  // 64 threads
  float n = 0.f, c = 0.f;
  for (int i = lane; i < 256; i += 64) { n += ws[2 * i]; c += ws[2 * i + 1]; }
#pragma unroll
  for (int off = 32; off >= 1; off >>= 1) {
    n += __shfl_xor(n, off);
    c += __shfl_xor(c, off);
  }
  if (lane == 0) outp[(size_t)Bsz * Tn * Vn] = n / fmaxf(c, 1.f);
}

extern "C" void kernel_launch(void* const* d_in, const int* in_sizes, int n_in,
                              void* d_out, int out_size, void* d_ws, size_t ws_size,
                              hipStream_t stream) {
  const float* phon = (const float*)d_in[0];
  const int*   cs   = (const int*)d_in[1];
  const float* emb  = (const float*)d_in[2];
  const float* Wrx  = (const float*)d_in[3];
  const float* brx  = (const float*)d_in[4];
  const float* Wrh  = (const float*)d_in[5];
  const float* brh  = (const float*)d_in[6];
  const float* Wzx  = (const float*)d_in[7];
  const float* bzx  = (const float*)d_in[8];
  const float* Wzh  = (const float*)d_in[9];
  const float* bzh  = (const float*)d_in[10];
  const float* Whx  = (const float*)d_in[11];
  const float* bhx  = (const float*)d_in[12];
  const float* Whh  = (const float*)d_in[13];
  const float* bhh  = (const float*)d_in[14];
  const float* Wpj  = (const float*)d_in[15];
  const float* bpj  = (const float*)d_in[16];
  float* ws = (float*)d_ws;

  hipLaunchKernelGGL(gru_kernel, dim3(Bsz / 16), dim3(256), 0, stream,
                     phon, cs, emb, Wrx, brx, Wrh, brh, Wzx, bzx, Wzh, bzh,
                     Whx, bhx, Whh, bhh, Wpj, bpj, ws, (float*)d_out);
  hipLaunchKernelGGL(loss_kernel, dim3(1), dim3(64), 0, stream, ws, (float*)d_out);
}